// Round 1
// baseline (908.779 us; speedup 1.0000x reference)
//
#include <hip/hip_runtime.h>

#define N_NODES 50000
#define N_EDGES 800000
#define DIM 128
#define NLAYERS 3
#define NGRAPH 512

// ---------------------------------------------------------------- degree
__global__ __launch_bounds__(256) void k_degree(const int* __restrict__ dst,
                                                int* __restrict__ cnt) {
    int i = blockIdx.x * blockDim.x + threadIdx.x;
    if (i < N_EDGES) atomicAdd(&cnt[dst[i]], 1);
}

// ---------------------------------------------------------------- scan (one block)
__global__ __launch_bounds__(1024) void k_scan(const int* __restrict__ cnt,
                                               int* __restrict__ off) {
    __shared__ int part[1024];
    const int T = 1024;
    int t = threadIdx.x;
    const int chunk = (N_NODES + T - 1) / T;  // 49
    int lo = t * chunk;
    int hi = lo + chunk; if (hi > N_NODES) hi = N_NODES;
    int s = 0;
    for (int i = lo; i < hi; ++i) s += cnt[i];
    part[t] = s;
    __syncthreads();
    for (int d = 1; d < T; d <<= 1) {
        int v = (t >= d) ? part[t - d] : 0;
        __syncthreads();
        part[t] += v;
        __syncthreads();
    }
    int run = (t == 0) ? 0 : part[t - 1];
    for (int i = lo; i < hi; ++i) { off[i] = run; run += cnt[i]; }
    if (t == T - 1) off[N_NODES] = part[T - 1];
}

// ---------------------------------------------------------------- scatter to CSR
__global__ __launch_bounds__(256) void k_scatter(const int* __restrict__ src,
                                                 const int* __restrict__ dst,
                                                 const int* __restrict__ off,
                                                 int* __restrict__ cursor,
                                                 int* __restrict__ src_s,
                                                 int* __restrict__ dst_s) {
    int i = blockIdx.x * blockDim.x + threadIdx.x;
    if (i < N_EDGES) {
        int d = dst[i];
        int pos = off[d] + atomicAdd(&cursor[d], 1);
        src_s[pos] = src[i];
        dst_s[pos] = d;
    }
}

// ---------------------------------------------------------------- 4-way GEMM: q,k,v,skip
// out[i][c] = sum_k x[i][k] * W[c][k] + b[c]   (x @ W.T + b)
__global__ __launch_bounds__(256) void k_gemm4(
    const float* __restrict__ x,
    const float* __restrict__ W0, const float* __restrict__ W1,
    const float* __restrict__ W2, const float* __restrict__ W3,
    const float* __restrict__ B0, const float* __restrict__ B1,
    const float* __restrict__ B2, const float* __restrict__ B3,
    float* __restrict__ O0, float* __restrict__ O1,
    float* __restrict__ O2, float* __restrict__ O3) {
    const int wsel = blockIdx.y;
    const float* W = (wsel == 0) ? W0 : (wsel == 1) ? W1 : (wsel == 2) ? W2 : W3;
    const float* B = (wsel == 0) ? B0 : (wsel == 1) ? B1 : (wsel == 2) ? B2 : B3;
    float* O       = (wsel == 0) ? O0 : (wsel == 1) ? O1 : (wsel == 2) ? O2 : O3;

    __shared__ float Wl[DIM][DIM];   // [k][c]  64 KB
    __shared__ float Xl[DIM][32];    // [k][r]  16 KB

    int t = threadIdx.x;
    // stage W transposed: thread -> (c = t>>1, half = t&1)
    {
        int c = t >> 1, h = t & 1;
        const float* wrow = W + c * DIM + h * 64;
#pragma unroll
        for (int j = 0; j < 16; ++j) {
            float4 w4 = ((const float4*)wrow)[j];
            int k0 = h * 64 + j * 4;
            Wl[k0 + 0][c] = w4.x; Wl[k0 + 1][c] = w4.y;
            Wl[k0 + 2][c] = w4.z; Wl[k0 + 3][c] = w4.w;
        }
    }
    int rb = blockIdx.x * 32;
    {
        int r = t >> 3, q8 = t & 7;
        int gr = rb + r;
        const float* xrow = x + (size_t)gr * DIM + q8 * 16;
#pragma unroll
        for (int j = 0; j < 4; ++j) {
            float4 v4 = make_float4(0.f, 0.f, 0.f, 0.f);
            if (gr < N_NODES) v4 = ((const float4*)xrow)[j];
            int k0 = q8 * 16 + j * 4;
            Xl[k0 + 0][r] = v4.x; Xl[k0 + 1][r] = v4.y;
            Xl[k0 + 2][r] = v4.z; Xl[k0 + 3][r] = v4.w;
        }
    }
    __syncthreads();

    int tr = t >> 5;   // 0..7  -> rows 4*tr..
    int tc = t & 31;   // 0..31 -> cols 4*tc..
    float acc[4][4] = {};
#pragma unroll 4
    for (int kk = 0; kk < DIM; ++kk) {
        float4 a4 = *(const float4*)&Xl[kk][tr * 4];
        float4 b4 = *(const float4*)&Wl[kk][tc * 4];
        acc[0][0] += a4.x * b4.x; acc[0][1] += a4.x * b4.y; acc[0][2] += a4.x * b4.z; acc[0][3] += a4.x * b4.w;
        acc[1][0] += a4.y * b4.x; acc[1][1] += a4.y * b4.y; acc[1][2] += a4.y * b4.z; acc[1][3] += a4.y * b4.w;
        acc[2][0] += a4.z * b4.x; acc[2][1] += a4.z * b4.y; acc[2][2] += a4.z * b4.z; acc[2][3] += a4.z * b4.w;
        acc[3][0] += a4.w * b4.x; acc[3][1] += a4.w * b4.y; acc[3][2] += a4.w * b4.z; acc[3][3] += a4.w * b4.w;
    }
    int c0 = tc * 4;
    float4 bias = *(const float4*)&B[c0];
#pragma unroll
    for (int i = 0; i < 4; ++i) {
        int gr = rb + tr * 4 + i;
        if (gr < N_NODES) {
            float4 o;
            o.x = acc[i][0] + bias.x; o.y = acc[i][1] + bias.y;
            o.z = acc[i][2] + bias.z; o.w = acc[i][3] + bias.w;
            *(float4*)&O[(size_t)gr * DIM + c0] = o;
        }
    }
}

// ---------------------------------------------------------------- per-edge alpha
__global__ __launch_bounds__(256) void k_alpha(const float* __restrict__ q,
                                               const float* __restrict__ k,
                                               const int* __restrict__ src_s,
                                               const int* __restrict__ dst_s,
                                               float* __restrict__ alpha_s) {
    int t = threadIdx.x;
    int grp = t >> 4, gl = t & 15;
    int i = blockIdx.x * 16 + grp;
    if (i >= N_EDGES) return;
    int s = src_s[i], d = dst_s[i];
    const float4* qr = (const float4*)(q + (size_t)d * DIM + gl * 8);
    const float4* kr = (const float4*)(k + (size_t)s * DIM + gl * 8);
    float4 q0 = qr[0], q1 = qr[1];
    float4 k0 = kr[0], k1 = kr[1];
    float p = q0.x * k0.x + q0.y * k0.y + q0.z * k0.z + q0.w * k0.w
            + q1.x * k1.x + q1.y * k1.y + q1.z * k1.z + q1.w * k1.w;
    p += __shfl_xor(p, 8, 16);
    p += __shfl_xor(p, 4, 16);
    p += __shfl_xor(p, 2, 16);
    p += __shfl_xor(p, 1, 16);
    if (gl == 0) alpha_s[i] = p * 0.08838834764831845f;  // 1/sqrt(128)
}

// ---------------------------------------------------------------- per-node softmax + aggregate (+skip+relu)
__global__ __launch_bounds__(256) void k_aggregate(const float* __restrict__ v,
                                                   const float* __restrict__ skip,
                                                   const float* __restrict__ alpha_s,
                                                   const int* __restrict__ src_s,
                                                   const int* __restrict__ off,
                                                   float* __restrict__ xout) {
    int t = threadIdx.x;
    int w = t >> 6, l = t & 63;
    int n = blockIdx.x * 4 + w;
    if (n >= N_NODES) return;
    int start = off[n], end = off[n + 1];

    float m = -INFINITY;
    for (int base = start; base < end; base += 64) {
        int idx = base + l;
        float a = (idx < end) ? alpha_s[idx] : -INFINITY;
        m = fmaxf(m, a);
    }
#pragma unroll
    for (int d = 32; d >= 1; d >>= 1) m = fmaxf(m, __shfl_xor(m, d, 64));

    float denom = 0.f;
    float acc0 = 0.f, acc1 = 0.f;
    for (int base = start; base < end; base += 64) {
        int idx = base + l;
        int len = end - base; if (len > 64) len = 64;
        float wgt = 0.f; int sv = 0;
        if (idx < end) {
            wgt = __expf(alpha_s[idx] - m);
            sv  = src_s[idx];
        }
        denom += wgt;
        for (int j = 0; j < len; ++j) {
            float wj = __shfl(wgt, j, 64);
            int   sj = __shfl(sv, j, 64);
            float2 vr = *(const float2*)(v + (size_t)sj * DIM + l * 2);
            acc0 += wj * vr.x;
            acc1 += wj * vr.y;
        }
    }
#pragma unroll
    for (int d = 32; d >= 1; d >>= 1) denom += __shfl_xor(denom, d, 64);

    float2 sk = *(const float2*)(skip + (size_t)n * DIM + l * 2);
    float o0 = sk.x, o1 = sk.y;
    if (denom > 0.f) { o0 += acc0 / denom; o1 += acc1 / denom; }
    o0 = fmaxf(o0, 0.f); o1 = fmaxf(o1, 0.f);
    *(float2*)(xout + (size_t)n * DIM + l * 2) = make_float2(o0, o1);
}

// ---------------------------------------------------------------- mean pool
__global__ __launch_bounds__(256) void k_pool(const float* __restrict__ x,
                                              const int* __restrict__ batch,
                                              float* __restrict__ out) {
    __shared__ float sacc[4][DIM];
    int g = blockIdx.x;
    int t = threadIdx.x;
    int w = t >> 6, l = t & 63;
    // lower_bound(g) and lower_bound(g+1) on sorted batch
    int lo = 0, hi = N_NODES;
    while (lo < hi) { int mid = (lo + hi) >> 1; if (batch[mid] < g) lo = mid + 1; else hi = mid; }
    int s0 = lo;
    hi = N_NODES;
    while (lo < hi) { int mid = (lo + hi) >> 1; if (batch[mid] < g + 1) lo = mid + 1; else hi = mid; }
    int s1 = lo;
    float a0 = 0.f, a1 = 0.f;
    for (int n = s0 + w; n < s1; n += 4) {
        float2 xr = *(const float2*)(x + (size_t)n * DIM + l * 2);
        a0 += xr.x; a1 += xr.y;
    }
    sacc[w][l * 2] = a0; sacc[w][l * 2 + 1] = a1;
    __syncthreads();
    if (t < DIM) {
        float s = sacc[0][t] + sacc[1][t] + sacc[2][t] + sacc[3][t];
        int cnt = s1 - s0;
        out[(size_t)g * DIM + t] = s / (float)((cnt > 0) ? cnt : 1);
    }
}

// ----------------------------------------------------------------
extern "C" void kernel_launch(void* const* d_in, const int* in_sizes, int n_in,
                              void* d_out, int out_size, void* d_ws, size_t ws_size,
                              hipStream_t stream) {
    const float* x0   = (const float*)d_in[0];
    const int*  eidx  = (const int*)d_in[1];
    const int*  batch = (const int*)d_in[2];
    const float* Wq = (const float*)d_in[3];
    const float* bq = (const float*)d_in[4];
    const float* Wk = (const float*)d_in[5];
    const float* bk = (const float*)d_in[6];
    const float* Wv = (const float*)d_in[7];
    const float* bv = (const float*)d_in[8];
    const float* Ws = (const float*)d_in[9];
    const float* bs = (const float*)d_in[10];
    float* out = (float*)d_out;

    const int* src = eidx;
    const int* dst = eidx + N_EDGES;

    char* ws = (char*)d_ws;
    size_t p = 0;
    auto alloc = [&](size_t bytes) -> void* {
        void* r = ws + p;
        p = (p + bytes + 255) & ~(size_t)255;
        return r;
    };
    int*   off    = (int*)alloc((N_NODES + 1) * sizeof(int));
    int*   cnt    = (int*)alloc(N_NODES * sizeof(int));
    int*   src_s  = (int*)alloc(N_EDGES * sizeof(int));
    int*   dst_s  = (int*)alloc(N_EDGES * sizeof(int));
    float* alphas = (float*)alloc(N_EDGES * sizeof(float));
    float* qb     = (float*)alloc((size_t)N_NODES * DIM * sizeof(float));
    float* kb     = (float*)alloc((size_t)N_NODES * DIM * sizeof(float));
    float* vb     = (float*)alloc((size_t)N_NODES * DIM * sizeof(float));
    float* s1     = (float*)alloc((size_t)N_NODES * DIM * sizeof(float));
    float* s2     = (float*)alloc((size_t)N_NODES * DIM * sizeof(float));

    // ---- build CSR (per launch; deterministic work)
    hipMemsetAsync(cnt, 0, N_NODES * sizeof(int), stream);
    k_degree<<<(N_EDGES + 255) / 256, 256, 0, stream>>>(dst, cnt);
    k_scan<<<1, 1024, 0, stream>>>(cnt, off);
    hipMemsetAsync(cnt, 0, N_NODES * sizeof(int), stream);
    k_scatter<<<(N_EDGES + 255) / 256, 256, 0, stream>>>(src, dst, off, cnt, src_s, dst_s);

    // ---- layers
    const float* xin = x0;
    float* xouts[NLAYERS] = { s1, s2, s1 };
    for (int l = 0; l < NLAYERS; ++l) {
        const float* wq = Wq + (size_t)l * DIM * DIM;
        const float* wk = Wk + (size_t)l * DIM * DIM;
        const float* wv = Wv + (size_t)l * DIM * DIM;
        const float* wsk = Ws + (size_t)l * DIM * DIM;
        const float* biq = bq + (size_t)l * DIM;
        const float* bik = bk + (size_t)l * DIM;
        const float* biv = bv + (size_t)l * DIM;
        const float* bis = bs + (size_t)l * DIM;
        float* xo = xouts[l];

        dim3 ggrid((N_NODES + 31) / 32, 4);
        k_gemm4<<<ggrid, 256, 0, stream>>>(xin, wq, wk, wv, wsk,
                                           biq, bik, biv, bis,
                                           qb, kb, vb, xo);
        k_alpha<<<(N_EDGES + 15) / 16, 256, 0, stream>>>(qb, kb, src_s, dst_s, alphas);
        k_aggregate<<<(N_NODES + 3) / 4, 256, 0, stream>>>(vb, xo, alphas, src_s, off, xo);
        xin = xo;
    }

    // ---- mean pool
    k_pool<<<NGRAPH, 256, 0, stream>>>(s1, batch, out);
}

// Round 2
// 661.884 us; speedup vs baseline: 1.3730x; 1.3730x over previous
//
#include <hip/hip_runtime.h>

#define N_NODES 50000
#define N_EDGES 800000
#define DIM 128
#define NLAYERS 3
#define NGRAPH 512

typedef __attribute__((ext_vector_type(8)))  __bf16 bf16x8;
typedef __attribute__((ext_vector_type(2)))  __bf16 bf16x2;
typedef __attribute__((ext_vector_type(16))) float  f32x16;

// ---------------------------------------------------------------- fp32 -> bf16 cast (8 elems/thread)
__global__ __launch_bounds__(256) void k_cast(const float* __restrict__ in,
                                              __bf16* __restrict__ out, int n) {
    int i = blockIdx.x * blockDim.x + threadIdx.x;
    int base = i * 8;
    if (base >= n) return;
    float4 a = *(const float4*)(in + base);
    float4 b = *(const float4*)(in + base + 4);
    bf16x8 o;
    o[0] = (__bf16)a.x; o[1] = (__bf16)a.y; o[2] = (__bf16)a.z; o[3] = (__bf16)a.w;
    o[4] = (__bf16)b.x; o[5] = (__bf16)b.y; o[6] = (__bf16)b.z; o[7] = (__bf16)b.w;
    *(bf16x8*)(out + base) = o;
}

// ---------------------------------------------------------------- degree
__global__ __launch_bounds__(256) void k_degree(const int* __restrict__ dst,
                                                int* __restrict__ cnt) {
    int i = blockIdx.x * blockDim.x + threadIdx.x;
    if (i < N_EDGES) atomicAdd(&cnt[dst[i]], 1);
}

// ---------------------------------------------------------------- scan (one block)
__global__ __launch_bounds__(1024) void k_scan(const int* __restrict__ cnt,
                                               int* __restrict__ off) {
    __shared__ int part[1024];
    const int T = 1024;
    int t = threadIdx.x;
    const int chunk = (N_NODES + T - 1) / T;
    int lo = t * chunk;
    int hi = lo + chunk; if (hi > N_NODES) hi = N_NODES;
    int s = 0;
    for (int i = lo; i < hi; ++i) s += cnt[i];
    part[t] = s;
    __syncthreads();
    for (int d = 1; d < T; d <<= 1) {
        int v = (t >= d) ? part[t - d] : 0;
        __syncthreads();
        part[t] += v;
        __syncthreads();
    }
    int run = (t == 0) ? 0 : part[t - 1];
    for (int i = lo; i < hi; ++i) { off[i] = run; run += cnt[i]; }
    if (t == T - 1) off[N_NODES] = part[T - 1];
}

// ---------------------------------------------------------------- scatter to CSR
__global__ __launch_bounds__(256) void k_scatter(const int* __restrict__ src,
                                                 const int* __restrict__ dst,
                                                 const int* __restrict__ off,
                                                 int* __restrict__ cursor,
                                                 int* __restrict__ src_s,
                                                 int* __restrict__ dst_s) {
    int i = blockIdx.x * blockDim.x + threadIdx.x;
    if (i < N_EDGES) {
        int d = dst[i];
        int pos = off[d] + atomicAdd(&cursor[d], 1);
        src_s[pos] = src[i];
        dst_s[pos] = d;
    }
}

// ---------------------------------------------------------------- MFMA GEMM: out = X @ W.T + b
// grid.x = node tiles (32 rows), grid.y = matrix select (q,k,v,skip)
// wave computes a 32x32 tile; A,B fragments load straight from global.
__global__ __launch_bounds__(256) void k_gemm_mfma(
    const __bf16* __restrict__ Xb,
    const __bf16* __restrict__ Wq, const __bf16* __restrict__ Wk,
    const __bf16* __restrict__ Wv, const __bf16* __restrict__ Wsk,
    const float* __restrict__ Bq, const float* __restrict__ Bk,
    const float* __restrict__ Bv, const float* __restrict__ Bs,
    __bf16* __restrict__ Oq, __bf16* __restrict__ Ok,
    __bf16* __restrict__ Ov, float* __restrict__ Osk) {
    const int wsel = blockIdx.y;
    const __bf16* W = (wsel == 0) ? Wq : (wsel == 1) ? Wk : (wsel == 2) ? Wv : Wsk;
    const float*  B = (wsel == 0) ? Bq : (wsel == 1) ? Bk : (wsel == 2) ? Bv : Bs;

    int t = threadIdx.x;
    int wave = t >> 6, l = t & 63;
    int lo5 = l & 31, hi = l >> 5;
    int row0 = blockIdx.x * 32;
    int col0 = wave * 32;

    // A: lane holds X[row0+lo5][kt*16 + hi*8 .. +7]; B: W[col0+lo5][same k range]
    const bf16x8* arow = (const bf16x8*)(Xb + (size_t)(row0 + lo5) * DIM + hi * 8);
    const bf16x8* brow = (const bf16x8*)(W  + (size_t)(col0 + lo5) * DIM + hi * 8);

    f32x16 acc = {};
#pragma unroll
    for (int kt = 0; kt < 8; ++kt)
        acc = __builtin_amdgcn_mfma_f32_32x32x16_bf16(arow[kt * 2], brow[kt * 2], acc, 0, 0, 0);

    float bias = B[col0 + lo5];
    if (wsel == 3) {
#pragma unroll
        for (int r = 0; r < 16; ++r) {
            int row = row0 + (r & 3) + 8 * (r >> 2) + 4 * hi;
            if (row < N_NODES)
                Osk[(size_t)row * DIM + col0 + lo5] = acc[r] + bias;
        }
    } else {
        __bf16* O = (wsel == 0) ? Oq : (wsel == 1) ? Ok : Ov;
#pragma unroll
        for (int r = 0; r < 16; ++r) {
            int row = row0 + (r & 3) + 8 * (r >> 2) + 4 * hi;
            if (row < N_NODES)
                O[(size_t)row * DIM + col0 + lo5] = (__bf16)(acc[r] + bias);
        }
    }
}

// ---------------------------------------------------------------- per-edge alpha (bf16 q,k)
__global__ __launch_bounds__(256) void k_alpha(const __bf16* __restrict__ q,
                                               const __bf16* __restrict__ k,
                                               const int* __restrict__ src_s,
                                               const int* __restrict__ dst_s,
                                               float* __restrict__ alpha_s) {
    int t = threadIdx.x;
    int grp = t >> 4, gl = t & 15;
    int i = blockIdx.x * 16 + grp;
    if (i >= N_EDGES) return;
    int s = src_s[i], d = dst_s[i];
    bf16x8 qv = *(const bf16x8*)(q + (size_t)d * DIM + gl * 8);
    bf16x8 kv = *(const bf16x8*)(k + (size_t)s * DIM + gl * 8);
    float p = 0.f;
#pragma unroll
    for (int j = 0; j < 8; ++j) p += (float)qv[j] * (float)kv[j];
    p += __shfl_xor(p, 8, 16);
    p += __shfl_xor(p, 4, 16);
    p += __shfl_xor(p, 2, 16);
    p += __shfl_xor(p, 1, 16);
    if (gl == 0) alpha_s[i] = p * 0.08838834764831845f;  // 1/sqrt(128)
}

// ---------------------------------------------------------------- per-node softmax + aggregate (+skip+relu)
// writes fp32 xout (residual path) and bf16 shadow (next layer's MFMA input)
__global__ __launch_bounds__(256) void k_aggregate(const __bf16* __restrict__ v,
                                                   const float* __restrict__ skip,
                                                   const float* __restrict__ alpha_s,
                                                   const int* __restrict__ src_s,
                                                   const int* __restrict__ off,
                                                   float* __restrict__ xout,
                                                   __bf16* __restrict__ xb) {
    int t = threadIdx.x;
    int w = t >> 6, l = t & 63;
    int n = blockIdx.x * 4 + w;
    if (n >= N_NODES) return;
    int start = off[n], end = off[n + 1];

    float m = -INFINITY;
    for (int base = start; base < end; base += 64) {
        int idx = base + l;
        float a = (idx < end) ? alpha_s[idx] : -INFINITY;
        m = fmaxf(m, a);
    }
#pragma unroll
    for (int d = 32; d >= 1; d >>= 1) m = fmaxf(m, __shfl_xor(m, d, 64));

    float denom = 0.f;
    float acc0 = 0.f, acc1 = 0.f;
    for (int base = start; base < end; base += 64) {
        int idx = base + l;
        int len = end - base; if (len > 64) len = 64;
        float wgt = 0.f; int sv = 0;
        if (idx < end) {
            wgt = __expf(alpha_s[idx] - m);
            sv  = src_s[idx];
        }
        denom += wgt;
        for (int j = 0; j < len; ++j) {
            float wj = __shfl(wgt, j, 64);
            int   sj = __shfl(sv, j, 64);
            bf16x2 vr = *(const bf16x2*)(v + (size_t)sj * DIM + l * 2);
            acc0 += wj * (float)vr[0];
            acc1 += wj * (float)vr[1];
        }
    }
#pragma unroll
    for (int d = 32; d >= 1; d >>= 1) denom += __shfl_xor(denom, d, 64);

    float2 sk = *(const float2*)(skip + (size_t)n * DIM + l * 2);
    float o0 = sk.x, o1 = sk.y;
    if (denom > 0.f) { o0 += acc0 / denom; o1 += acc1 / denom; }
    o0 = fmaxf(o0, 0.f); o1 = fmaxf(o1, 0.f);
    *(float2*)(xout + (size_t)n * DIM + l * 2) = make_float2(o0, o1);
    bf16x2 ob; ob[0] = (__bf16)o0; ob[1] = (__bf16)o1;
    *(bf16x2*)(xb + (size_t)n * DIM + l * 2) = ob;
}

// ---------------------------------------------------------------- mean pool
__global__ __launch_bounds__(256) void k_pool(const float* __restrict__ x,
                                              const int* __restrict__ batch,
                                              float* __restrict__ out) {
    __shared__ float sacc[4][DIM];
    int g = blockIdx.x;
    int t = threadIdx.x;
    int w = t >> 6, l = t & 63;
    int lo = 0, hi = N_NODES;
    while (lo < hi) { int mid = (lo + hi) >> 1; if (batch[mid] < g) lo = mid + 1; else hi = mid; }
    int s0 = lo;
    hi = N_NODES;
    while (lo < hi) { int mid = (lo + hi) >> 1; if (batch[mid] < g + 1) lo = mid + 1; else hi = mid; }
    int s1 = lo;
    float a0 = 0.f, a1 = 0.f;
    for (int n = s0 + w; n < s1; n += 4) {
        float2 xr = *(const float2*)(x + (size_t)n * DIM + l * 2);
        a0 += xr.x; a1 += xr.y;
    }
    sacc[w][l * 2] = a0; sacc[w][l * 2 + 1] = a1;
    __syncthreads();
    if (t < DIM) {
        float s = sacc[0][t] + sacc[1][t] + sacc[2][t] + sacc[3][t];
        int cnt = s1 - s0;
        out[(size_t)g * DIM + t] = s / (float)((cnt > 0) ? cnt : 1);
    }
}

// ----------------------------------------------------------------
extern "C" void kernel_launch(void* const* d_in, const int* in_sizes, int n_in,
                              void* d_out, int out_size, void* d_ws, size_t ws_size,
                              hipStream_t stream) {
    const float* x0   = (const float*)d_in[0];
    const int*  eidx  = (const int*)d_in[1];
    const int*  batch = (const int*)d_in[2];
    const float* Wq = (const float*)d_in[3];
    const float* bq = (const float*)d_in[4];
    const float* Wk = (const float*)d_in[5];
    const float* bk = (const float*)d_in[6];
    const float* Wv = (const float*)d_in[7];
    const float* bv = (const float*)d_in[8];
    const float* Ws = (const float*)d_in[9];
    const float* bs = (const float*)d_in[10];
    float* out = (float*)d_out;

    const int* src = eidx;
    const int* dst = eidx + N_EDGES;

    char* ws = (char*)d_ws;
    size_t p = 0;
    auto alloc = [&](size_t bytes) -> void* {
        void* r = ws + p;
        p = (p + bytes + 255) & ~(size_t)255;
        return r;
    };
    int*    off    = (int*)alloc((N_NODES + 1) * sizeof(int));
    int*    cnt    = (int*)alloc(N_NODES * sizeof(int));
    int*    src_s  = (int*)alloc(N_EDGES * sizeof(int));
    int*    dst_s  = (int*)alloc(N_EDGES * sizeof(int));
    float*  alphas = (float*)alloc(N_EDGES * sizeof(float));
    __bf16* Xb     = (__bf16*)alloc((size_t)N_NODES * DIM * sizeof(__bf16));
    __bf16* qb     = (__bf16*)alloc((size_t)N_NODES * DIM * sizeof(__bf16));
    __bf16* kb     = (__bf16*)alloc((size_t)N_NODES * DIM * sizeof(__bf16));
    __bf16* vb     = (__bf16*)alloc((size_t)N_NODES * DIM * sizeof(__bf16));
    float*  s1     = (float*)alloc((size_t)N_NODES * DIM * sizeof(float));
    float*  s2     = (float*)alloc((size_t)N_NODES * DIM * sizeof(float));
    __bf16* Wqb    = (__bf16*)alloc((size_t)NLAYERS * DIM * DIM * sizeof(__bf16));
    __bf16* Wkb    = (__bf16*)alloc((size_t)NLAYERS * DIM * DIM * sizeof(__bf16));
    __bf16* Wvb    = (__bf16*)alloc((size_t)NLAYERS * DIM * DIM * sizeof(__bf16));
    __bf16* Wsb    = (__bf16*)alloc((size_t)NLAYERS * DIM * DIM * sizeof(__bf16));

    // ---- casts (x0 and all layer weights)
    {
        int nx = N_NODES * DIM;
        k_cast<<<(nx / 8 + 255) / 256, 256, 0, stream>>>(x0, Xb, nx);
        int nw = NLAYERS * DIM * DIM;
        int gw = (nw / 8 + 255) / 256;
        k_cast<<<gw, 256, 0, stream>>>(Wq, Wqb, nw);
        k_cast<<<gw, 256, 0, stream>>>(Wk, Wkb, nw);
        k_cast<<<gw, 256, 0, stream>>>(Wv, Wvb, nw);
        k_cast<<<gw, 256, 0, stream>>>(Ws, Wsb, nw);
    }

    // ---- build CSR
    hipMemsetAsync(cnt, 0, N_NODES * sizeof(int), stream);
    k_degree<<<(N_EDGES + 255) / 256, 256, 0, stream>>>(dst, cnt);
    k_scan<<<1, 1024, 0, stream>>>(cnt, off);
    hipMemsetAsync(cnt, 0, N_NODES * sizeof(int), stream);
    k_scatter<<<(N_EDGES + 255) / 256, 256, 0, stream>>>(src, dst, off, cnt, src_s, dst_s);

    // ---- layers
    float* xouts[NLAYERS] = { s1, s2, s1 };
    for (int l = 0; l < NLAYERS; ++l) {
        const __bf16* wq = Wqb + (size_t)l * DIM * DIM;
        const __bf16* wk = Wkb + (size_t)l * DIM * DIM;
        const __bf16* wv = Wvb + (size_t)l * DIM * DIM;
        const __bf16* wsk = Wsb + (size_t)l * DIM * DIM;
        const float* biq = bq + (size_t)l * DIM;
        const float* bik = bk + (size_t)l * DIM;
        const float* biv = bv + (size_t)l * DIM;
        const float* bis = bs + (size_t)l * DIM;
        float* xo = xouts[l];

        dim3 ggrid((N_NODES + 31) / 32, 4);
        k_gemm_mfma<<<ggrid, 256, 0, stream>>>(Xb, wq, wk, wv, wsk,
                                               biq, bik, biv, bis,
                                               qb, kb, vb, xo);
        k_alpha<<<(N_EDGES + 15) / 16, 256, 0, stream>>>(qb, kb, src_s, dst_s, alphas);
        k_aggregate<<<(N_NODES + 3) / 4, 256, 0, stream>>>(vb, xo, alphas, src_s, off, xo, Xb);
    }

    // ---- mean pool
    k_pool<<<NGRAPH, 256, 0, stream>>>(s1, batch, out);
}

// Round 3
// 523.482 us; speedup vs baseline: 1.7360x; 1.2644x over previous
//
#include <hip/hip_runtime.h>

#define N_NODES 50000
#define N_EDGES 800000
#define DIM 128
#define NLAYERS 3
#define NGRAPH 512
#define SCAN_NB ((N_NODES + 255) / 256)   // 196

typedef __attribute__((ext_vector_type(8)))  __bf16 bf16x8;
typedef __attribute__((ext_vector_type(2)))  __bf16 bf16x2;
typedef __attribute__((ext_vector_type(16))) float  f32x16;

// ---------------------------------------------------------------- fp32 -> bf16 cast (8 elems/thread)
__global__ __launch_bounds__(256) void k_cast(const float* __restrict__ in,
                                              __bf16* __restrict__ out, int n) {
    int i = blockIdx.x * blockDim.x + threadIdx.x;
    int base = i * 8;
    if (base >= n) return;
    float4 a = *(const float4*)(in + base);
    float4 b = *(const float4*)(in + base + 4);
    bf16x8 o;
    o[0] = (__bf16)a.x; o[1] = (__bf16)a.y; o[2] = (__bf16)a.z; o[3] = (__bf16)a.w;
    o[4] = (__bf16)b.x; o[5] = (__bf16)b.y; o[6] = (__bf16)b.z; o[7] = (__bf16)b.w;
    *(bf16x8*)(out + base) = o;
}

// ---------------------------------------------------------------- degree
__global__ __launch_bounds__(256) void k_degree(const int* __restrict__ dst,
                                                int* __restrict__ cnt) {
    int i = blockIdx.x * blockDim.x + threadIdx.x;
    if (i < N_EDGES) atomicAdd(&cnt[dst[i]], 1);
}

// ---------------------------------------------------------------- hierarchical scan
__global__ __launch_bounds__(256) void k_scan1(const int* __restrict__ cnt,
                                               int* __restrict__ off,
                                               int* __restrict__ bsum) {
    __shared__ int s[256];
    int b = blockIdx.x, t = threadIdx.x;
    int i = b * 256 + t;
    int v = (i < N_NODES) ? cnt[i] : 0;
    s[t] = v; __syncthreads();
#pragma unroll
    for (int d = 1; d < 256; d <<= 1) {
        int nv = (t >= d) ? s[t - d] : 0;
        __syncthreads();
        s[t] += nv;
        __syncthreads();
    }
    if (i < N_NODES) off[i] = s[t] - v;        // exclusive within block
    if (t == 255) bsum[b] = s[255];
}

__global__ __launch_bounds__(256) void k_scan2(const int* __restrict__ bsum,
                                               int* __restrict__ boff,
                                               int* __restrict__ offN) {
    __shared__ int s[256];
    int t = threadIdx.x;
    int v = (t < SCAN_NB) ? bsum[t] : 0;
    s[t] = v; __syncthreads();
#pragma unroll
    for (int d = 1; d < 256; d <<= 1) {
        int nv = (t >= d) ? s[t - d] : 0;
        __syncthreads();
        s[t] += nv;
        __syncthreads();
    }
    boff[t] = s[t] - v;
    if (t == 255) *offN = s[255];              // off[N_NODES] = total edges
}

__global__ __launch_bounds__(256) void k_scan3(int* __restrict__ off,
                                               const int* __restrict__ boff) {
    int b = blockIdx.x, t = threadIdx.x;
    int i = b * 256 + t;
    if (i < N_NODES) off[i] += boff[b];
}

// ---------------------------------------------------------------- scatter to CSR
__global__ __launch_bounds__(256) void k_scatter(const int* __restrict__ src,
                                                 const int* __restrict__ dst,
                                                 const int* __restrict__ off,
                                                 int* __restrict__ cursor,
                                                 int* __restrict__ src_s,
                                                 int* __restrict__ dst_s) {
    int i = blockIdx.x * blockDim.x + threadIdx.x;
    if (i < N_EDGES) {
        int d = dst[i];
        int pos = off[d] + atomicAdd(&cursor[d], 1);
        src_s[pos] = src[i];
        dst_s[pos] = d;
    }
}

// ---------------------------------------------------------------- MFMA GEMM: out = X @ W.T + b
__global__ __launch_bounds__(256) void k_gemm_mfma(
    const __bf16* __restrict__ Xb,
    const __bf16* __restrict__ Wq, const __bf16* __restrict__ Wk,
    const __bf16* __restrict__ Wv, const __bf16* __restrict__ Wsk,
    const float* __restrict__ Bq, const float* __restrict__ Bk,
    const float* __restrict__ Bv, const float* __restrict__ Bs,
    __bf16* __restrict__ Oq, __bf16* __restrict__ Ok,
    __bf16* __restrict__ Ov, float* __restrict__ Osk) {
    const int wsel = blockIdx.y;
    const __bf16* W = (wsel == 0) ? Wq : (wsel == 1) ? Wk : (wsel == 2) ? Wv : Wsk;
    const float*  B = (wsel == 0) ? Bq : (wsel == 1) ? Bk : (wsel == 2) ? Bv : Bs;

    int t = threadIdx.x;
    int wave = t >> 6, l = t & 63;
    int lo5 = l & 31, hi = l >> 5;
    int row0 = blockIdx.x * 32;
    int col0 = wave * 32;

    const bf16x8* arow = (const bf16x8*)(Xb + (size_t)(row0 + lo5) * DIM + hi * 8);
    const bf16x8* brow = (const bf16x8*)(W  + (size_t)(col0 + lo5) * DIM + hi * 8);

    f32x16 acc = {};
#pragma unroll
    for (int kt = 0; kt < 8; ++kt)
        acc = __builtin_amdgcn_mfma_f32_32x32x16_bf16(arow[kt * 2], brow[kt * 2], acc, 0, 0, 0);

    float bias = B[col0 + lo5];
    if (wsel == 3) {
#pragma unroll
        for (int r = 0; r < 16; ++r) {
            int row = row0 + (r & 3) + 8 * (r >> 2) + 4 * hi;
            if (row < N_NODES)
                Osk[(size_t)row * DIM + col0 + lo5] = acc[r] + bias;
        }
    } else {
        __bf16* O = (wsel == 0) ? Oq : (wsel == 1) ? Ok : Ov;
#pragma unroll
        for (int r = 0; r < 16; ++r) {
            int row = row0 + (r & 3) + 8 * (r >> 2) + 4 * hi;
            if (row < N_NODES)
                O[(size_t)row * DIM + col0 + lo5] = (__bf16)(acc[r] + bias);
        }
    }
}

// ---------------------------------------------------------------- per-edge alpha (bf16 q,k)
__global__ __launch_bounds__(256) void k_alpha(const __bf16* __restrict__ q,
                                               const __bf16* __restrict__ k,
                                               const int* __restrict__ src_s,
                                               const int* __restrict__ dst_s,
                                               float* __restrict__ alpha_s) {
    int t = threadIdx.x;
    int grp = t >> 4, gl = t & 15;
    int i = blockIdx.x * 16 + grp;
    if (i >= N_EDGES) return;
    int s = src_s[i], d = dst_s[i];
    bf16x8 qv = *(const bf16x8*)(q + (size_t)d * DIM + gl * 8);
    bf16x8 kv = *(const bf16x8*)(k + (size_t)s * DIM + gl * 8);
    float p = 0.f;
#pragma unroll
    for (int j = 0; j < 8; ++j) p += (float)qv[j] * (float)kv[j];
    p += __shfl_xor(p, 8, 16);
    p += __shfl_xor(p, 4, 16);
    p += __shfl_xor(p, 2, 16);
    p += __shfl_xor(p, 1, 16);
    if (gl == 0) alpha_s[i] = p * 0.08838834764831845f;  // 1/sqrt(128)
}

// ---------------------------------------------------------------- per-node softmax + aggregate (+skip+relu)
// 4x16-lane groups: group g handles edges base+4t+g, reads v-row as bf16x8.
__global__ __launch_bounds__(256) void k_aggregate(const __bf16* __restrict__ v,
                                                   const float* __restrict__ skip,
                                                   const float* __restrict__ alpha_s,
                                                   const int* __restrict__ src_s,
                                                   const int* __restrict__ off,
                                                   float* __restrict__ xout,
                                                   __bf16* __restrict__ xb) {
    int t = threadIdx.x;
    int w = t >> 6, l = t & 63;
    int n = blockIdx.x * 4 + w;
    if (n >= N_NODES) return;
    int start = off[n], end = off[n + 1];
    int g = l >> 4, gl = l & 15;

    // pass 1: segment max
    float m = -INFINITY;
    for (int base = start; base < end; base += 64) {
        int idx = base + l;
        float a = (idx < end) ? alpha_s[idx] : -INFINITY;
        m = fmaxf(m, a);
    }
#pragma unroll
    for (int d = 32; d >= 1; d >>= 1) m = fmaxf(m, __shfl_xor(m, d, 64));

    // pass 2: exp weights + weighted aggregation (4 edges in flight)
    float denom = 0.f;
    float facc[8] = {};
    for (int base = start; base < end; base += 64) {
        int idx = base + l;
        float wgt = 0.f; int sv = 0;
        if (idx < end) {
            wgt = __expf(alpha_s[idx] - m);
            sv  = src_s[idx];
        }
        denom += wgt;
        int len = end - base; if (len > 64) len = 64;
        for (int tt = 0; tt < 16; ++tt) {
            int e = 4 * tt + g;          // uniform within 16-lane group
            if (e >= len) break;
            float wj = __shfl(wgt, 4 * tt + g, 64);
            int   sj = __shfl(sv,  4 * tt + g, 64);
            bf16x8 vr = *(const bf16x8*)(v + (size_t)sj * DIM + gl * 8);
#pragma unroll
            for (int j = 0; j < 8; ++j) facc[j] += wj * (float)vr[j];
        }
    }
    // combine 4 groups + denom reduce
#pragma unroll
    for (int j = 0; j < 8; ++j) {
        facc[j] += __shfl_xor(facc[j], 16, 64);
        facc[j] += __shfl_xor(facc[j], 32, 64);
    }
#pragma unroll
    for (int d = 32; d >= 1; d >>= 1) denom += __shfl_xor(denom, d, 64);
    float inv = (denom > 0.f) ? 1.f / denom : 0.f;

    if (g == 0) {
        const float* skrow = skip + (size_t)n * DIM + gl * 8;
        float4 s0 = *(const float4*)(skrow);
        float4 s1 = *(const float4*)(skrow + 4);
        float o[8] = { s0.x, s0.y, s0.z, s0.w, s1.x, s1.y, s1.z, s1.w };
        bf16x8 ob;
#pragma unroll
        for (int j = 0; j < 8; ++j) {
            float val = fmaxf(o[j] + facc[j] * inv, 0.f);
            o[j] = val; ob[j] = (__bf16)val;
        }
        float* xrow = xout + (size_t)n * DIM + gl * 8;
        *(float4*)(xrow)     = make_float4(o[0], o[1], o[2], o[3]);
        *(float4*)(xrow + 4) = make_float4(o[4], o[5], o[6], o[7]);
        *(bf16x8*)(xb + (size_t)n * DIM + gl * 8) = ob;
    }
}

// ---------------------------------------------------------------- mean pool
__global__ __launch_bounds__(256) void k_pool(const float* __restrict__ x,
                                              const int* __restrict__ batch,
                                              float* __restrict__ out) {
    __shared__ float sacc[4][DIM];
    int g = blockIdx.x;
    int t = threadIdx.x;
    int w = t >> 6, l = t & 63;
    int lo = 0, hi = N_NODES;
    while (lo < hi) { int mid = (lo + hi) >> 1; if (batch[mid] < g) lo = mid + 1; else hi = mid; }
    int s0 = lo;
    hi = N_NODES;
    while (lo < hi) { int mid = (lo + hi) >> 1; if (batch[mid] < g + 1) lo = mid + 1; else hi = mid; }
    int s1 = lo;
    float a0 = 0.f, a1 = 0.f;
    for (int n = s0 + w; n < s1; n += 4) {
        float2 xr = *(const float2*)(x + (size_t)n * DIM + l * 2);
        a0 += xr.x; a1 += xr.y;
    }
    sacc[w][l * 2] = a0; sacc[w][l * 2 + 1] = a1;
    __syncthreads();
    if (t < DIM) {
        float s = sacc[0][t] + sacc[1][t] + sacc[2][t] + sacc[3][t];
        int cnt = s1 - s0;
        out[(size_t)g * DIM + t] = s / (float)((cnt > 0) ? cnt : 1);
    }
}

// ----------------------------------------------------------------
extern "C" void kernel_launch(void* const* d_in, const int* in_sizes, int n_in,
                              void* d_out, int out_size, void* d_ws, size_t ws_size,
                              hipStream_t stream) {
    const float* x0   = (const float*)d_in[0];
    const int*  eidx  = (const int*)d_in[1];
    const int*  batch = (const int*)d_in[2];
    const float* Wq = (const float*)d_in[3];
    const float* bq = (const float*)d_in[4];
    const float* Wk = (const float*)d_in[5];
    const float* bk = (const float*)d_in[6];
    const float* Wv = (const float*)d_in[7];
    const float* bv = (const float*)d_in[8];
    const float* Ws = (const float*)d_in[9];
    const float* bs = (const float*)d_in[10];
    float* out = (float*)d_out;

    const int* src = eidx;
    const int* dst = eidx + N_EDGES;

    char* ws = (char*)d_ws;
    size_t p = 0;
    auto alloc = [&](size_t bytes) -> void* {
        void* r = ws + p;
        p = (p + bytes + 255) & ~(size_t)255;
        return r;
    };
    int*    off    = (int*)alloc((N_NODES + 1) * sizeof(int));
    int*    cnt    = (int*)alloc(N_NODES * sizeof(int));
    int*    bsum   = (int*)alloc(256 * sizeof(int));
    int*    boff   = (int*)alloc(256 * sizeof(int));
    int*    src_s  = (int*)alloc(N_EDGES * sizeof(int));
    int*    dst_s  = (int*)alloc(N_EDGES * sizeof(int));
    float*  alphas = (float*)alloc(N_EDGES * sizeof(float));
    __bf16* Xb     = (__bf16*)alloc((size_t)N_NODES * DIM * sizeof(__bf16));
    __bf16* qb     = (__bf16*)alloc((size_t)N_NODES * DIM * sizeof(__bf16));
    __bf16* kb     = (__bf16*)alloc((size_t)N_NODES * DIM * sizeof(__bf16));
    __bf16* vb     = (__bf16*)alloc((size_t)N_NODES * DIM * sizeof(__bf16));
    float*  s1     = (float*)alloc((size_t)N_NODES * DIM * sizeof(float));
    float*  s2     = (float*)alloc((size_t)N_NODES * DIM * sizeof(float));
    __bf16* Wqb    = (__bf16*)alloc((size_t)NLAYERS * DIM * DIM * sizeof(__bf16));
    __bf16* Wkb    = (__bf16*)alloc((size_t)NLAYERS * DIM * DIM * sizeof(__bf16));
    __bf16* Wvb    = (__bf16*)alloc((size_t)NLAYERS * DIM * DIM * sizeof(__bf16));
    __bf16* Wsb    = (__bf16*)alloc((size_t)NLAYERS * DIM * DIM * sizeof(__bf16));

    // ---- casts
    {
        int nx = N_NODES * DIM;
        k_cast<<<(nx / 8 + 255) / 256, 256, 0, stream>>>(x0, Xb, nx);
        int nw = NLAYERS * DIM * DIM;
        int gw = (nw / 8 + 255) / 256;
        k_cast<<<gw, 256, 0, stream>>>(Wq, Wqb, nw);
        k_cast<<<gw, 256, 0, stream>>>(Wk, Wkb, nw);
        k_cast<<<gw, 256, 0, stream>>>(Wv, Wvb, nw);
        k_cast<<<gw, 256, 0, stream>>>(Ws, Wsb, nw);
    }

    // ---- build CSR
    hipMemsetAsync(cnt, 0, N_NODES * sizeof(int), stream);
    k_degree<<<(N_EDGES + 255) / 256, 256, 0, stream>>>(dst, cnt);
    k_scan1<<<SCAN_NB, 256, 0, stream>>>(cnt, off, bsum);
    k_scan2<<<1, 256, 0, stream>>>(bsum, boff, off + N_NODES);
    k_scan3<<<SCAN_NB, 256, 0, stream>>>(off, boff);
    hipMemsetAsync(cnt, 0, N_NODES * sizeof(int), stream);
    k_scatter<<<(N_EDGES + 255) / 256, 256, 0, stream>>>(src, dst, off, cnt, src_s, dst_s);

    // ---- layers
    float* xouts[NLAYERS] = { s1, s2, s1 };
    for (int l = 0; l < NLAYERS; ++l) {
        const __bf16* wq = Wqb + (size_t)l * DIM * DIM;
        const __bf16* wk = Wkb + (size_t)l * DIM * DIM;
        const __bf16* wv = Wvb + (size_t)l * DIM * DIM;
        const __bf16* wsk = Wsb + (size_t)l * DIM * DIM;
        const float* biq = bq + (size_t)l * DIM;
        const float* bik = bk + (size_t)l * DIM;
        const float* biv = bv + (size_t)l * DIM;
        const float* bis = bs + (size_t)l * DIM;
        float* xo = xouts[l];

        dim3 ggrid((N_NODES + 31) / 32, 4);
        k_gemm_mfma<<<ggrid, 256, 0, stream>>>(Xb, wq, wk, wv, wsk,
                                               biq, bik, biv, bis,
                                               qb, kb, vb, xo);
        k_alpha<<<(N_EDGES + 15) / 16, 256, 0, stream>>>(qb, kb, src_s, dst_s, alphas);
        k_aggregate<<<(N_NODES + 3) / 4, 256, 0, stream>>>(vb, xo, alphas, src_s, off, xo, Xb);
    }

    // ---- mean pool
    k_pool<<<NGRAPH, 256, 0, stream>>>(s1, batch, out);
}

// Round 4
// 466.627 us; speedup vs baseline: 1.9475x; 1.1218x over previous
//
#include <hip/hip_runtime.h>

#define N_NODES 50000
#define N_EDGES 800000
#define DIM 128
#define NLAYERS 3
#define NGRAPH 512
#define SCAN_NB ((N_NODES + 255) / 256)   // 196

typedef __attribute__((ext_vector_type(8)))  __bf16 bf16x8;
typedef __attribute__((ext_vector_type(16))) float  f32x16;

// ---------------------------------------------------------------- fp32 -> bf16 cast
__global__ __launch_bounds__(256) void k_cast(const float* __restrict__ in,
                                              __bf16* __restrict__ out, int n) {
    int i = blockIdx.x * blockDim.x + threadIdx.x;
    int base = i * 8;
    if (base >= n) return;
    float4 a = *(const float4*)(in + base);
    float4 b = *(const float4*)(in + base + 4);
    bf16x8 o;
    o[0] = (__bf16)a.x; o[1] = (__bf16)a.y; o[2] = (__bf16)a.z; o[3] = (__bf16)a.w;
    o[4] = (__bf16)b.x; o[5] = (__bf16)b.y; o[6] = (__bf16)b.z; o[7] = (__bf16)b.w;
    *(bf16x8*)(out + base) = o;
}

// ---------------------------------------------------------------- degree
__global__ __launch_bounds__(256) void k_degree(const int* __restrict__ dst,
                                                int* __restrict__ cnt) {
    int i = blockIdx.x * blockDim.x + threadIdx.x;
    if (i < N_EDGES) atomicAdd(&cnt[dst[i]], 1);
}

// ---------------------------------------------------------------- hierarchical scan
__global__ __launch_bounds__(256) void k_scan1(const int* __restrict__ cnt,
                                               int* __restrict__ off,
                                               int* __restrict__ bsum) {
    __shared__ int s[256];
    int b = blockIdx.x, t = threadIdx.x;
    int i = b * 256 + t;
    int v = (i < N_NODES) ? cnt[i] : 0;
    s[t] = v; __syncthreads();
#pragma unroll
    for (int d = 1; d < 256; d <<= 1) {
        int nv = (t >= d) ? s[t - d] : 0;
        __syncthreads();
        s[t] += nv;
        __syncthreads();
    }
    if (i < N_NODES) off[i] = s[t] - v;
    if (t == 255) bsum[b] = s[255];
}

__global__ __launch_bounds__(256) void k_scan2(const int* __restrict__ bsum,
                                               int* __restrict__ boff,
                                               int* __restrict__ offN) {
    __shared__ int s[256];
    int t = threadIdx.x;
    int v = (t < SCAN_NB) ? bsum[t] : 0;
    s[t] = v; __syncthreads();
#pragma unroll
    for (int d = 1; d < 256; d <<= 1) {
        int nv = (t >= d) ? s[t - d] : 0;
        __syncthreads();
        s[t] += nv;
        __syncthreads();
    }
    boff[t] = s[t] - v;
    if (t == 255) *offN = s[255];
}

__global__ __launch_bounds__(256) void k_scan3(int* __restrict__ off,
                                               const int* __restrict__ boff) {
    int b = blockIdx.x, t = threadIdx.x;
    int i = b * 256 + t;
    if (i < N_NODES) off[i] += boff[b];
}

// ---------------------------------------------------------------- scatter to CSR (src only)
__global__ __launch_bounds__(256) void k_scatter(const int* __restrict__ src,
                                                 const int* __restrict__ dst,
                                                 const int* __restrict__ off,
                                                 int* __restrict__ cursor,
                                                 int* __restrict__ src_s) {
    int i = blockIdx.x * blockDim.x + threadIdx.x;
    if (i < N_EDGES) {
        int d = dst[i];
        int pos = off[d] + atomicAdd(&cursor[d], 1);
        src_s[pos] = src[i];
    }
}

// ---------------------------------------------------------------- MFMA GEMM: out = X @ W.T + b
// q -> Oq [node][128] bf16; k,v -> Okv interleaved [node][k 128 | v 128] bf16; skip -> fp32
__global__ __launch_bounds__(256) void k_gemm_mfma(
    const __bf16* __restrict__ Xb,
    const __bf16* __restrict__ Wq, const __bf16* __restrict__ Wk,
    const __bf16* __restrict__ Wv, const __bf16* __restrict__ Wsk,
    const float* __restrict__ Bq, const float* __restrict__ Bk,
    const float* __restrict__ Bv, const float* __restrict__ Bs,
    __bf16* __restrict__ Oq, __bf16* __restrict__ Okv,
    float* __restrict__ Osk) {
    const int wsel = blockIdx.y;
    const __bf16* W = (wsel == 0) ? Wq : (wsel == 1) ? Wk : (wsel == 2) ? Wv : Wsk;
    const float*  B = (wsel == 0) ? Bq : (wsel == 1) ? Bk : (wsel == 2) ? Bv : Bs;

    int t = threadIdx.x;
    int wave = t >> 6, l = t & 63;
    int lo5 = l & 31, hi = l >> 5;
    int row0 = blockIdx.x * 32;
    int col0 = wave * 32;

    const bf16x8* arow = (const bf16x8*)(Xb + (size_t)(row0 + lo5) * DIM + hi * 8);
    const bf16x8* brow = (const bf16x8*)(W  + (size_t)(col0 + lo5) * DIM + hi * 8);

    f32x16 acc = {};
#pragma unroll
    for (int kt = 0; kt < 8; ++kt)
        acc = __builtin_amdgcn_mfma_f32_32x32x16_bf16(arow[kt * 2], brow[kt * 2], acc, 0, 0, 0);

    float bias = B[col0 + lo5];
    if (wsel == 3) {
#pragma unroll
        for (int r = 0; r < 16; ++r) {
            int row = row0 + (r & 3) + 8 * (r >> 2) + 4 * hi;
            if (row < N_NODES)
                Osk[(size_t)row * DIM + col0 + lo5] = acc[r] + bias;
        }
    } else {
        __bf16* O; size_t stride; int coff;
        if (wsel == 0) { O = Oq;  stride = DIM;     coff = 0; }
        else           { O = Okv; stride = 2 * DIM; coff = (wsel == 2) ? DIM : 0; }
#pragma unroll
        for (int r = 0; r < 16; ++r) {
            int row = row0 + (r & 3) + 8 * (r >> 2) + 4 * hi;
            if (row < N_NODES)
                O[(size_t)row * stride + coff + col0 + lo5] = (__bf16)(acc[r] + bias);
        }
    }
}

// ---------------------------------------------------------------- fused alpha + softmax + aggregate (+skip+relu)
// 1 wave per node, 4x16-lane groups; group g handles edges start+g, start+g+4, ...
// online softmax per group, butterfly merge across groups.
__global__ __launch_bounds__(256) void k_edge_fused(const __bf16* __restrict__ q,
                                                    const __bf16* __restrict__ kv,
                                                    const float* __restrict__ skip,
                                                    const int* __restrict__ src_s,
                                                    const int* __restrict__ off,
                                                    float* __restrict__ xout,
                                                    __bf16* __restrict__ xb) {
    int t = threadIdx.x;
    int w = t >> 6, l = t & 63;
    int n = blockIdx.x * 4 + w;
    if (n >= N_NODES) return;
    int start = off[n], end = off[n + 1];
    int g = l >> 4, gl = l & 15;

    bf16x8 qv = *(const bf16x8*)(q + (size_t)n * DIM + gl * 8);

    float m = -INFINITY, denom = 0.f;
    float facc[8] = {};
    for (int e = start + g; e < end; e += 4) {
        int s = src_s[e];
        const __bf16* kvrow = kv + (size_t)s * (2 * DIM) + gl * 8;
        bf16x8 krow = *(const bf16x8*)(kvrow);
        bf16x8 vrow = *(const bf16x8*)(kvrow + DIM);
        float p = 0.f;
#pragma unroll
        for (int j = 0; j < 8; ++j) p += (float)qv[j] * (float)krow[j];
        p += __shfl_xor(p, 8, 16);
        p += __shfl_xor(p, 4, 16);
        p += __shfl_xor(p, 2, 16);
        p += __shfl_xor(p, 1, 16);
        p *= 0.08838834764831845f;   // 1/sqrt(128)
        if (p > m) {
            float sc = __expf(m - p);   // 0 on first edge (m=-inf)
            denom = denom * sc + 1.f;
#pragma unroll
            for (int j = 0; j < 8; ++j) facc[j] = facc[j] * sc + (float)vrow[j];
            m = p;
        } else {
            float wgt = __expf(p - m);
            denom += wgt;
#pragma unroll
            for (int j = 0; j < 8; ++j) facc[j] += wgt * (float)vrow[j];
        }
    }

    // merge the 4 groups (butterfly over lane bits 4,5) with softmax rescale
#pragma unroll
    for (int dlt = 16; dlt <= 32; dlt <<= 1) {
        float m_o = __shfl_xor(m, dlt, 64);
        float d_o = __shfl_xor(denom, dlt, 64);
        float f_o[8];
#pragma unroll
        for (int j = 0; j < 8; ++j) f_o[j] = __shfl_xor(facc[j], dlt, 64);
        float newm = fmaxf(m, m_o);
        float s_s = (m == newm)   ? 1.f : __expf(m - newm);
        float s_o = (m_o == newm) ? 1.f : __expf(m_o - newm);
        denom = denom * s_s + d_o * s_o;
#pragma unroll
        for (int j = 0; j < 8; ++j) facc[j] = facc[j] * s_s + f_o[j] * s_o;
        m = newm;
    }
    float inv = (denom > 0.f) ? 1.f / denom : 0.f;

    if (g == 0) {
        const float* skrow = skip + (size_t)n * DIM + gl * 8;
        float4 s0 = *(const float4*)(skrow);
        float4 s1 = *(const float4*)(skrow + 4);
        float o[8] = { s0.x, s0.y, s0.z, s0.w, s1.x, s1.y, s1.z, s1.w };
        bf16x8 ob;
#pragma unroll
        for (int j = 0; j < 8; ++j) {
            float val = fmaxf(o[j] + facc[j] * inv, 0.f);
            o[j] = val; ob[j] = (__bf16)val;
        }
        float* xrow = xout + (size_t)n * DIM + gl * 8;
        *(float4*)(xrow)     = make_float4(o[0], o[1], o[2], o[3]);
        *(float4*)(xrow + 4) = make_float4(o[4], o[5], o[6], o[7]);
        *(bf16x8*)(xb + (size_t)n * DIM + gl * 8) = ob;
    }
}

// ---------------------------------------------------------------- mean pool
__global__ __launch_bounds__(256) void k_pool(const float* __restrict__ x,
                                              const int* __restrict__ batch,
                                              float* __restrict__ out) {
    __shared__ float sacc[4][DIM];
    int g = blockIdx.x;
    int t = threadIdx.x;
    int w = t >> 6, l = t & 63;
    int lo = 0, hi = N_NODES;
    while (lo < hi) { int mid = (lo + hi) >> 1; if (batch[mid] < g) lo = mid + 1; else hi = mid; }
    int s0 = lo;
    hi = N_NODES;
    while (lo < hi) { int mid = (lo + hi) >> 1; if (batch[mid] < g + 1) lo = mid + 1; else hi = mid; }
    int s1 = lo;
    float a0 = 0.f, a1 = 0.f;
    for (int n = s0 + w; n < s1; n += 4) {
        float2 xr = *(const float2*)(x + (size_t)n * DIM + l * 2);
        a0 += xr.x; a1 += xr.y;
    }
    sacc[w][l * 2] = a0; sacc[w][l * 2 + 1] = a1;
    __syncthreads();
    if (t < DIM) {
        float s = sacc[0][t] + sacc[1][t] + sacc[2][t] + sacc[3][t];
        int cnt = s1 - s0;
        out[(size_t)g * DIM + t] = s / (float)((cnt > 0) ? cnt : 1);
    }
}

// ----------------------------------------------------------------
extern "C" void kernel_launch(void* const* d_in, const int* in_sizes, int n_in,
                              void* d_out, int out_size, void* d_ws, size_t ws_size,
                              hipStream_t stream) {
    const float* x0   = (const float*)d_in[0];
    const int*  eidx  = (const int*)d_in[1];
    const int*  batch = (const int*)d_in[2];
    const float* Wq = (const float*)d_in[3];
    const float* bq = (const float*)d_in[4];
    const float* Wk = (const float*)d_in[5];
    const float* bk = (const float*)d_in[6];
    const float* Wv = (const float*)d_in[7];
    const float* bv = (const float*)d_in[8];
    const float* Ws = (const float*)d_in[9];
    const float* bs = (const float*)d_in[10];
    float* out = (float*)d_out;

    const int* src = eidx;
    const int* dst = eidx + N_EDGES;

    char* ws = (char*)d_ws;
    size_t p = 0;
    auto alloc = [&](size_t bytes) -> void* {
        void* r = ws + p;
        p = (p + bytes + 255) & ~(size_t)255;
        return r;
    };
    int*    off    = (int*)alloc((N_NODES + 1) * sizeof(int));
    int*    cnt    = (int*)alloc(N_NODES * sizeof(int));
    int*    bsum   = (int*)alloc(256 * sizeof(int));
    int*    boff   = (int*)alloc(256 * sizeof(int));
    int*    src_s  = (int*)alloc(N_EDGES * sizeof(int));
    __bf16* Xb     = (__bf16*)alloc((size_t)N_NODES * DIM * sizeof(__bf16));
    __bf16* qb     = (__bf16*)alloc((size_t)N_NODES * DIM * sizeof(__bf16));
    __bf16* kvb    = (__bf16*)alloc((size_t)N_NODES * 2 * DIM * sizeof(__bf16));
    float*  s1     = (float*)alloc((size_t)N_NODES * DIM * sizeof(float));
    __bf16* Wqb    = (__bf16*)alloc((size_t)NLAYERS * DIM * DIM * sizeof(__bf16));
    __bf16* Wkb    = (__bf16*)alloc((size_t)NLAYERS * DIM * DIM * sizeof(__bf16));
    __bf16* Wvb    = (__bf16*)alloc((size_t)NLAYERS * DIM * DIM * sizeof(__bf16));
    __bf16* Wsb    = (__bf16*)alloc((size_t)NLAYERS * DIM * DIM * sizeof(__bf16));

    // ---- casts
    {
        int nx = N_NODES * DIM;
        k_cast<<<(nx / 8 + 255) / 256, 256, 0, stream>>>(x0, Xb, nx);
        int nw = NLAYERS * DIM * DIM;
        int gw = (nw / 8 + 255) / 256;
        k_cast<<<gw, 256, 0, stream>>>(Wq, Wqb, nw);
        k_cast<<<gw, 256, 0, stream>>>(Wk, Wkb, nw);
        k_cast<<<gw, 256, 0, stream>>>(Wv, Wvb, nw);
        k_cast<<<gw, 256, 0, stream>>>(Ws, Wsb, nw);
    }

    // ---- build CSR
    hipMemsetAsync(cnt, 0, N_NODES * sizeof(int), stream);
    k_degree<<<(N_EDGES + 255) / 256, 256, 0, stream>>>(dst, cnt);
    k_scan1<<<SCAN_NB, 256, 0, stream>>>(cnt, off, bsum);
    k_scan2<<<1, 256, 0, stream>>>(bsum, boff, off + N_NODES);
    k_scan3<<<SCAN_NB, 256, 0, stream>>>(off, boff);
    hipMemsetAsync(cnt, 0, N_NODES * sizeof(int), stream);
    k_scatter<<<(N_EDGES + 255) / 256, 256, 0, stream>>>(src, dst, off, cnt, src_s);

    // ---- layers
    for (int l = 0; l < NLAYERS; ++l) {
        const __bf16* wq = Wqb + (size_t)l * DIM * DIM;
        const __bf16* wk = Wkb + (size_t)l * DIM * DIM;
        const __bf16* wv = Wvb + (size_t)l * DIM * DIM;
        const __bf16* wsk = Wsb + (size_t)l * DIM * DIM;
        const float* biq = bq + (size_t)l * DIM;
        const float* bik = bk + (size_t)l * DIM;
        const float* biv = bv + (size_t)l * DIM;
        const float* bis = bs + (size_t)l * DIM;

        dim3 ggrid((N_NODES + 31) / 32, 4);
        k_gemm_mfma<<<ggrid, 256, 0, stream>>>(Xb, wq, wk, wv, wsk,
                                               biq, bik, biv, bis,
                                               qb, kvb, s1);
        k_edge_fused<<<(N_NODES + 3) / 4, 256, 0, stream>>>(qb, kvb, s1, src_s, off, s1, Xb);
    }

    // ---- mean pool
    k_pool<<<NGRAPH, 256, 0, stream>>>(s1, batch, out);
}